// Round 6
// baseline (217.542 us; speedup 1.0000x reference)
//
#include <hip/hip_runtime.h>

#define NB 16
#define C  256
#define H  64
#define W  64
#define E  32
#define F  768
#define HW 4096
#define K5 2048
#define XROWS 4224   // 64 pad + 4096 + 64 pad

typedef __attribute__((ext_vector_type(4))) float f32x4;
typedef __attribute__((ext_vector_type(8))) short s16x8;

__device__ inline unsigned short to_bf16(float f) {
  union { float f; unsigned u; } v; v.f = f;
  unsigned u = v.u;
  u += 0x7fff + ((u >> 16) & 1);
  return (unsigned short)(u >> 16);
}

__device__ inline float from_bf16(unsigned short s) {
  union { unsigned u; float f; } v; v.u = ((unsigned)s) << 16;
  return v.f;
}

__device__ inline void gload16(const void* g, void* l) {
  __builtin_amdgcn_global_load_lds((const __attribute__((address_space(1))) unsigned int*)g,
                                   (__attribute__((address_space(3))) unsigned int*)l, 16, 0, 0);
}

// ---------------------------------------------------------------------------
// Kernel A: fused t1 (MFMA) -> t3 (9x9 dw, VALU) -> t4 (5x1 grouped, regs).
// One block per (n, 4-channel group); 1024 blocks, 4 waves.
// xs: bf16, double-buffered, col-unit swizzle u = (w>>3) ^ ((h>>3)&7) so the
//     MFMA B-fragment column reads (8 rows x 16 cols) are bank-conflict-free.
// t1s: f32 [40][72] zero-padded borders (branch-free 9x9 window).
// t3s: bf16 [36][64], one channel at a time; t4 accumulates in registers.
// LDS = 32512 B -> 4 blocks/CU (grid-capped at 4 anyway).
// ---------------------------------------------------------------------------
__global__ __launch_bounds__(256, 4) void k_t4(const float* __restrict__ x,
                                               const float* __restrict__ p1,
                                               const float* __restrict__ p3,
                                               const float* __restrict__ p4,
                                               unsigned short* __restrict__ t4b) {
  const int n  = blockIdx.x >> 6;
  const int g  = blockIdx.x & 63;
  const int c0 = g * 4;
  const int tid = threadIdx.x;
  const int lane = tid & 63;
  const int wv = tid >> 6;

  __shared__ __align__(16) unsigned short xs[2][64][64];  // 16384 B (swizzled)
  __shared__ __align__(16) float t1s[40][72];             // 11520 B
  __shared__ __align__(16) unsigned short t3s[36][64];    //  4608 B

  // zero t1s/t3s once: pads stay zero, interiors rewritten per q
  {
    float* f = &t1s[0][0];
    for (int i = tid; i < 40 * 72; i += 256) f[i] = 0.f;
    unsigned* u = (unsigned*)&t3s[0][0];
    for (int i = tid; i < (36 * 64) / 2; i += 256) u[i] = 0u;
  }

  // A-fragments: p1^T, af[m][kc]: row r = lane&15 -> e = m*16+r, k = kc*32+(lane>>4)*8+j
  s16x8 afr[2][2];
  {
    const int r  = lane & 15;
    const int kb = (lane >> 4) * 8;
#pragma unroll
    for (int m = 0; m < 2; ++m)
#pragma unroll
      for (int kc = 0; kc < 2; ++kc) {
        s16x8 tmp;
#pragma unroll
        for (int j = 0; j < 8; ++j)
          tmp[j] = (short)to_bf16(p1[(kc * 32 + kb + j) * 32 + m * 16 + r]);
        afr[m][kc] = tmp;
      }
  }

  // prologue: stage channel c0 into xs[0]
  {
    const float* xp = x + ((size_t)(n * C + c0)) * HW;
#pragma unroll
    for (int t = 0; t < 2; ++t) {
      int uid = tid + 256 * t;          // 512 units of 8 cols
      int h = uid >> 3, uc = uid & 7;
      float4 v0 = *(const float4*)(xp + h * 64 + uc * 8);
      float4 v1 = *(const float4*)(xp + h * 64 + uc * 8 + 4);
      unsigned short b[8] = {to_bf16(v0.x), to_bf16(v0.y), to_bf16(v0.z), to_bf16(v0.w),
                             to_bf16(v1.x), to_bf16(v1.y), to_bf16(v1.z), to_bf16(v1.w)};
      *(uint4*)((char*)&xs[0][0][0] + h * 128 + ((uc ^ ((h >> 3) & 7)) * 16)) = *(const uint4*)b;
    }
  }
  __syncthreads();

  const int e_t = tid >> 3;  // 0..31 (t3/t4 row)
  const int wq  = tid & 7;   // 8-col group

  float tacc[4][8];
#pragma unroll
  for (int qo = 0; qo < 4; ++qo)
#pragma unroll
    for (int k = 0; k < 8; ++k) tacc[qo][k] = 0.f;

  auto t4_acc = [&](int ci) {
#pragma unroll
    for (int u = 0; u < 5; ++u) {
      uint4 v = *(const uint4*)&t3s[e_t + u][wq * 8];
      const unsigned short* vs = (const unsigned short*)&v;
      float vf[8];
#pragma unroll
      for (int k = 0; k < 8; ++k) vf[k] = from_bf16(vs[k]);
#pragma unroll
      for (int qo = 0; qo < 4; ++qo) {
        float wvt = p4[(c0 + qo) * 20 + ci * 5 + u];
#pragma unroll
        for (int k = 0; k < 8; ++k) tacc[qo][k] += vf[k] * wvt;
      }
    }
  };

  int buf = 0;
#pragma unroll
  for (int q = 0; q < 4; ++q) {
    // 1. prefetch next channel into regs (issue early; written after barrier)
    float4 pv0, pv1, pv2, pv3;
    int h0 = 0, u0 = 0, h1 = 0, u1 = 0;
    if (q < 3) {
      const float* xn = x + ((size_t)(n * C + c0 + q + 1)) * HW;
      int uid = tid;       h0 = uid >> 3; u0 = uid & 7;
      pv0 = *(const float4*)(xn + h0 * 64 + u0 * 8);
      pv1 = *(const float4*)(xn + h0 * 64 + u0 * 8 + 4);
      uid = tid + 256;     h1 = uid >> 3; u1 = uid & 7;
      pv2 = *(const float4*)(xn + h1 * 64 + u1 * 8);
      pv3 = *(const float4*)(xn + h1 * 64 + u1 * 8 + 4);
    }
    // 2. t1 via MFMA: wave wv covers cols [16wv, 16wv+16)
    {
      const int wcol = wv * 16 + (lane & 15);
      f32x4 cf[2] = {{0.f, 0.f, 0.f, 0.f}, {0.f, 0.f, 0.f, 0.f}};
#pragma unroll
      for (int kc = 0; kc < 2; ++kc) {
        const int kb = kc * 32 + (lane >> 4) * 8;
        const char* base = (const char*)&xs[buf][0][0] +
                           kb * 128 + (((wcol >> 3) ^ ((kb >> 3) & 7)) * 16) + (wcol & 7) * 2;
        s16x8 bfrag;
#pragma unroll
        for (int j = 0; j < 8; ++j)
          bfrag[j] = *(const short*)(base + j * 128);
        cf[0] = __builtin_amdgcn_mfma_f32_16x16x32_bf16(afr[0][kc], bfrag, cf[0], 0, 0, 0);
        cf[1] = __builtin_amdgcn_mfma_f32_16x16x32_bf16(afr[1][kc], bfrag, cf[1], 0, 0, 0);
      }
#pragma unroll
      for (int m = 0; m < 2; ++m)
#pragma unroll
        for (int j = 0; j < 4; ++j)
          t1s[4 + m * 16 + (lane >> 4) * 4 + j][4 + wcol] = cf[m][j];
    }
    // 3. t4 accumulation for previous channel's t3 (t3s stable since last sync)
    if (q > 0) t4_acc(q - 1);
    __syncthreads();
    // 5. write prefetched channel into xs[buf^1]
    if (q < 3) {
      unsigned short b0[8] = {to_bf16(pv0.x), to_bf16(pv0.y), to_bf16(pv0.z), to_bf16(pv0.w),
                              to_bf16(pv1.x), to_bf16(pv1.y), to_bf16(pv1.z), to_bf16(pv1.w)};
      *(uint4*)((char*)&xs[buf ^ 1][0][0] + h0 * 128 + ((u0 ^ ((h0 >> 3) & 7)) * 16)) = *(const uint4*)b0;
      unsigned short b1[8] = {to_bf16(pv2.x), to_bf16(pv2.y), to_bf16(pv2.z), to_bf16(pv2.w),
                              to_bf16(pv3.x), to_bf16(pv3.y), to_bf16(pv3.z), to_bf16(pv3.w)};
      *(uint4*)((char*)&xs[buf ^ 1][0][0] + h1 * 128 + ((u1 ^ ((h1 >> 3) & 7)) * 16)) = *(const uint4*)b1;
    }
    // 6. t3: 9x9 depthwise on channel q, f32 window from t1s
    {
      const float* w3 = p3 + (c0 + q) * 81;
      float o[8];
#pragma unroll
      for (int k = 0; k < 8; ++k) o[k] = 0.f;
#pragma unroll
      for (int i = 0; i < 9; ++i) {
        float win[16];
        const float* r = &t1s[e_t + i][8 * wq];
        *(float4*)&win[0]  = *(const float4*)(r);
        *(float4*)&win[4]  = *(const float4*)(r + 4);
        *(float4*)&win[8]  = *(const float4*)(r + 8);
        *(float4*)&win[12] = *(const float4*)(r + 12);
#pragma unroll
        for (int j = 0; j < 9; ++j) {
          float wt = w3[i * 9 + j];
#pragma unroll
          for (int k = 0; k < 8; ++k) o[k] += win[j + k] * wt;
        }
      }
      unsigned short ob[8];
#pragma unroll
      for (int k = 0; k < 8; ++k) ob[k] = to_bf16(o[k]);
      *(uint4*)&t3s[2 + e_t][wq * 8] = *(const uint4*)ob;
    }
    __syncthreads();
    buf ^= 1;
  }
  t4_acc(3);
  // epilogue: write t4 (bf16)
#pragma unroll
  for (int qo = 0; qo < 4; ++qo) {
    unsigned short ob[8];
#pragma unroll
    for (int k = 0; k < 8; ++k) ob[k] = to_bf16(tacc[qo][k]);
    *(uint4*)(t4b + ((size_t)(n * C + c0 + qo)) * (E * W) + e_t * 64 + wq * 8) = *(const uint4*)ob;
  }
}

// ---------------------------------------------------------------------------
// p5 [2048][768] f32 -> p5t [768][2048] bf16 (transpose + convert)
// ---------------------------------------------------------------------------
__global__ __launch_bounds__(256) void k_p5t(const float* __restrict__ p5,
                                             unsigned short* __restrict__ p5t) {
  const int f0 = blockIdx.x * 64;
  const int k0 = blockIdx.y * 64;
  const int tid = threadIdx.x;
  __shared__ __align__(16) unsigned short ls[64][264];
  int fl = tid & 63, k4 = tid >> 6;
  for (int i = 0; i < 16; ++i) {
    int kl = k4 * 16 + i;
    ls[fl][kl] = to_bf16(p5[(size_t)(k0 + kl) * F + f0 + fl]);
  }
  __syncthreads();
#pragma unroll
  for (int j = 0; j < 2; ++j) {
    int chunk = tid + 256 * j;
    int row = chunk >> 3, slot = chunk & 7;
    *(uint4*)(p5t + (size_t)(f0 + row) * K5 + k0 + slot * 8) = *(const uint4*)&ls[row][slot * 8];
  }
}

// ---------------------------------------------------------------------------
// x [n][c][h][w] f32 -> xt [n][64 + h*64+w + 64][c] bf16, zero pads
// ---------------------------------------------------------------------------
__global__ __launch_bounds__(256) void k_xt(const float* __restrict__ x,
                                            unsigned short* __restrict__ xt) {
  const int hi = blockIdx.x;   // 0..65
  const int n = blockIdx.y;
  const int tid = threadIdx.x;
  unsigned short* dst = xt + ((size_t)n * XROWS + hi * 64) * C;
  if (hi == 0 || hi == 65) {
    uint4 z = make_uint4(0, 0, 0, 0);
    uint4* d4 = (uint4*)dst;
#pragma unroll
    for (int i = 0; i < 8; ++i) d4[tid + 256 * i] = z;
    return;
  }
  const int h = hi - 1;
  __shared__ __align__(16) unsigned short ls[64][264];
  const float* xp = x + ((size_t)n * C) * HW + h * 64;
  int w = tid & 63, c4 = tid >> 6;
  for (int i = 0; i < 64; ++i) {
    int c = c4 * 64 + i;
    ls[w][c] = to_bf16(xp[(size_t)c * HW + w]);
  }
  __syncthreads();
#pragma unroll
  for (int j = 0; j < 8; ++j) {
    int chunk = tid + 256 * j;          // 2048 chunks of 16B
    int row = chunk >> 5, slot = chunk & 31;
    *(uint4*)(dst + row * C + slot * 8) = *(const uint4*)&ls[row][slot * 8];
  }
}

// ---------------------------------------------------------------------------
// k_t5m: t5[4096][768] f32 = t4b[4096][2048]bf16 x p5t^T.  64x64 tile ->
// 768 blocks (3/CU) for TLP; 4 waves as 2x2, wave-tile 32x32.
// ---------------------------------------------------------------------------
__global__ __launch_bounds__(256) void k_t5m(const unsigned short* __restrict__ A,
                                             const unsigned short* __restrict__ Bt,
                                             float* __restrict__ Cout) {
  const int n0 = blockIdx.x * 64;   // 12
  const int m0 = blockIdx.y * 64;   // 64
  const int tid = threadIdx.x;
  const int lane = tid & 63;
  const int wave = tid >> 6;
  const int wm = wave >> 1, wn = wave & 1;
  __shared__ __align__(16) short As[4096];
  __shared__ __align__(16) short Bs[4096];
  f32x4 acc[2][2] = {};
  const int lr = lane >> 3;
  const int ls = lane & 7;

  for (int k0 = 0; k0 < K5; k0 += 64) {
#pragma unroll
    for (int i = 0; i < 2; ++i) {
      int inst = wave * 2 + i;       // 0..7
      int r = inst * 8 + lr;         // 0..63
      int sw = ls ^ (r & 7);
      gload16((const char*)(A + (size_t)(m0 + r) * K5 + k0) + sw * 16,
              (char*)As + inst * 1024);
      gload16((const char*)(Bt + (size_t)(n0 + r) * K5 + k0) + sw * 16,
              (char*)Bs + inst * 1024);
    }
    __syncthreads();
#pragma unroll
    for (int kh = 0; kh < 2; ++kh) {
      s16x8 af[2], bf[2];
#pragma unroll
      for (int mi = 0; mi < 2; ++mi) {
        int row = wm * 32 + mi * 16 + (lane & 15);
        int byte = (row * 128 + kh * 64 + (lane >> 4) * 16) ^ ((row & 7) << 4);
        af[mi] = *(const s16x8*)((const char*)As + byte);
      }
#pragma unroll
      for (int ni = 0; ni < 2; ++ni) {
        int row = wn * 32 + ni * 16 + (lane & 15);
        int byte = (row * 128 + kh * 64 + (lane >> 4) * 16) ^ ((row & 7) << 4);
        bf[ni] = *(const s16x8*)((const char*)Bs + byte);
      }
#pragma unroll
      for (int mi = 0; mi < 2; ++mi)
#pragma unroll
        for (int ni = 0; ni < 2; ++ni)
          acc[mi][ni] = __builtin_amdgcn_mfma_f32_16x16x32_bf16(af[mi], bf[ni], acc[mi][ni], 0, 0, 0);
    }
    __syncthreads();
  }
#pragma unroll
  for (int mi = 0; mi < 2; ++mi) {
    int rbase = m0 + wm * 32 + mi * 16 + (lane >> 4) * 4;
#pragma unroll
    for (int ni = 0; ni < 2; ++ni) {
      int col = n0 + wn * 32 + ni * 16 + (lane & 15);
#pragma unroll
      for (int q = 0; q < 4; ++q)
        Cout[(size_t)(rbase + q) * F + col] = acc[mi][ni][q];
    }
  }
}

// ---------------------------------------------------------------------------
// k_t6: t5 f32 -> 3-tap dw conv (original f order) -> scale -> bf16 in f' order
// f' = kk*256 + c2  (f = 3*c2 + kk)
// ---------------------------------------------------------------------------
__global__ __launch_bounds__(256) void k_t6(const float* __restrict__ t5,
                                            const float* __restrict__ p6,
                                            unsigned short* __restrict__ t6b) {
  int idx = blockIdx.x * 256 + threadIdx.x;
  if (idx >= NB * C * F) return;
  int fp = idx % F;
  int nc = idx / F;
  int c = nc & 255;
  int c2 = fp & 255;
  int kk = fp >> 8;
  int f = 3 * c2 + kk;
  const float* row = t5 + (size_t)nc * F;
  const float* wt = p6 + c * 3;
  float acc = row[f] * wt[1];
  if (f > 0) acc += row[f - 1] * wt[0];
  if (f < F - 1) acc += row[f + 1] * wt[2];
  t6b[idx] = to_bf16(acc * 0.03608439182435161f);
}

// ---------------------------------------------------------------------------
// k_outm: out[n][256][4096] f32 = t6b[n][256][768] x B' (from xt, shifted rows)
// ---------------------------------------------------------------------------
__global__ __launch_bounds__(256) void k_outm(const unsigned short* __restrict__ t6b,
                                              const unsigned short* __restrict__ xt,
                                              float* __restrict__ outp) {
  const int p0 = blockIdx.x * 128;   // 32
  const int m0 = blockIdx.y * 128;   // 2
  const int n  = blockIdx.z;         // 16
  const int tid = threadIdx.x;
  const int lane = tid & 63;
  const int wave = tid >> 6;
  const int wm = wave >> 1, wn = wave & 1;
  __shared__ __align__(16) short As[8192];
  __shared__ __align__(16) short Bs[8192];
  f32x4 acc[4][4] = {};
  const int lr = lane >> 3;
  const int ls = lane & 7;
  const unsigned short* Abase = t6b + (size_t)(n * C) * F;
  const unsigned short* Xbase = xt + (size_t)n * XROWS * C;

  for (int kt = 0; kt < 12; ++kt) {
    int k0 = kt * 64;
    int kk = k0 >> 8;
    int c20 = k0 & 255;
#pragma unroll
    for (int i = 0; i < 4; ++i) {
      int inst = wave * 4 + i;
      int r = inst * 8 + lr;
      int sw = ls ^ (r & 7);
      gload16((const char*)(Abase + (size_t)(m0 + r) * F + k0) + sw * 16,
              (char*)As + inst * 1024);
      gload16((const char*)(Xbase + (size_t)(p0 + r + (kk << 6)) * C + c20) + sw * 16,
              (char*)Bs + inst * 1024);
    }
    __syncthreads();
#pragma unroll
    for (int kh = 0; kh < 2; ++kh) {
      s16x8 af[4], bf[4];
#pragma unroll
      for (int mi = 0; mi < 4; ++mi) {
        int row = wm * 64 + mi * 16 + (lane & 15);
        int byte = (row * 128 + kh * 64 + (lane >> 4) * 16) ^ ((row & 7) << 4);
        af[mi] = *(const s16x8*)((const char*)As + byte);
      }
#pragma unroll
      for (int ni = 0; ni < 4; ++ni) {
        int row = wn * 64 + ni * 16 + (lane & 15);
        int byte = (row * 128 + kh * 64 + (lane >> 4) * 16) ^ ((row & 7) << 4);
        bf[ni] = *(const s16x8*)((const char*)Bs + byte);
      }
#pragma unroll
      for (int mi = 0; mi < 4; ++mi)
#pragma unroll
        for (int ni = 0; ni < 4; ++ni)
          acc[mi][ni] = __builtin_amdgcn_mfma_f32_16x16x32_bf16(af[mi], bf[ni], acc[mi][ni], 0, 0, 0);
    }
    __syncthreads();
  }
  float* obase = outp + (size_t)(n * C) * HW;
#pragma unroll
  for (int mi = 0; mi < 4; ++mi) {
    int rbase = m0 + wm * 64 + mi * 16 + (lane >> 4) * 4;
#pragma unroll
    for (int ni = 0; ni < 4; ++ni) {
      int col = p0 + wn * 64 + ni * 16 + (lane & 15);
#pragma unroll
      for (int q = 0; q < 4; ++q)
        obase[(size_t)(rbase + q) * HW + col] = acc[mi][ni][q];
    }
  }
}

extern "C" void kernel_launch(void* const* d_in, const int* in_sizes, int n_in,
                              void* d_out, int out_size, void* d_ws, size_t ws_size,
                              hipStream_t stream) {
  (void)in_sizes; (void)n_in; (void)out_size; (void)ws_size;
  const float* x  = (const float*)d_in[0];
  const float* p1 = (const float*)d_in[1];
  const float* p3 = (const float*)d_in[2];
  const float* p4 = (const float*)d_in[3];
  const float* p5 = (const float*)d_in[4];
  const float* p6 = (const float*)d_in[5];
  float* out = (float*)d_out;

  char* ws = (char*)d_ws;
  // region [0, 34.6MB): early = {t4b, p5t, t5}; late (after k_t6) = xt
  unsigned short* t4b = (unsigned short*)ws;                          // 16.8 MB
  unsigned short* p5t = (unsigned short*)(ws + 16777216);             //  3.1 MB
  float*          t5  = (float*)(ws + 19922944);                      // 12.6 MB
  unsigned short* xt  = (unsigned short*)ws;                          // 34.6 MB (overlays t4b/p5t/t5)
  unsigned short* t6b = (unsigned short*)(ws + 34603008);             //  6.3 MB

  k_t4 <<<dim3(NB * 64), 256, 0, stream>>>(x, p1, p3, p4, t4b);
  k_p5t<<<dim3(12, 32), 256, 0, stream>>>(p5, p5t);
  k_t5m<<<dim3(12, 64), 256, 0, stream>>>(t4b, p5t, t5);
  k_t6 <<<dim3((NB * C * F + 255) / 256), 256, 0, stream>>>(t5, p6, t6b);
  k_xt <<<dim3(66, NB), 256, 0, stream>>>(x, xt);
  k_outm<<<dim3(32, 2, NB), 256, 0, stream>>>(t6b, xt, out);
}

// Round 7
// 167.991 us; speedup vs baseline: 1.2950x; 1.2950x over previous
//
#include <hip/hip_runtime.h>

#define NB 16
#define C  256
#define H  64
#define W  64
#define E  32
#define F  768
#define HW 4096
#define K5 2048
#define XROWS 4224   // 64 pad + 4096 + 64 pad

typedef __attribute__((ext_vector_type(4))) float f32x4;
typedef __attribute__((ext_vector_type(8))) short s16x8;

__device__ inline unsigned short to_bf16(float f) {
  union { float f; unsigned u; } v; v.f = f;
  unsigned u = v.u;
  u += 0x7fff + ((u >> 16) & 1);
  return (unsigned short)(u >> 16);
}

__device__ inline float from_bf16(unsigned short s) {
  union { unsigned u; float f; } v; v.u = ((unsigned)s) << 16;
  return v.f;
}

__device__ inline void gload16(const void* g, void* l) {
  __builtin_amdgcn_global_load_lds((const __attribute__((address_space(1))) unsigned int*)g,
                                   (__attribute__((address_space(3))) unsigned int*)l, 16, 0, 0);
}

// ---------------------------------------------------------------------------
// k_t1: t1b[nc][e*64+w] bf16 = sum_h x[nc][h][w] * p1[h][e].
// One block per (n,c); p1^T staged once in LDS (broadcast reads); x reads
// coalesced with 4x L1 reuse across the 4 waves. No spills, high occupancy.
// ---------------------------------------------------------------------------
__global__ __launch_bounds__(256) void k_t1(const float* __restrict__ x,
                                            const float* __restrict__ p1,
                                            unsigned short* __restrict__ t1b) {
  const int nc = blockIdx.x;
  const int tid = threadIdx.x;
  const int w = tid & 63;
  const int e0 = tid >> 6;  // 0..3
  __shared__ __align__(16) float p1t[32][68];  // 8.5 KB, p1t[e][h], +4 pad
  for (int i = tid; i < 2048; i += 256) {
    int h = i >> 5, e = i & 31;      // coalesced global read
    p1t[e][h] = p1[i];
  }
  __syncthreads();
  const float* xp = x + (size_t)nc * HW;
  float acc[8] = {0.f, 0.f, 0.f, 0.f, 0.f, 0.f, 0.f, 0.f};
#pragma unroll
  for (int hb = 0; hb < 4; ++hb) {
    float xv[16];
#pragma unroll
    for (int j = 0; j < 16; ++j) xv[j] = xp[(hb * 16 + j) * 64 + w];
#pragma unroll
    for (int i = 0; i < 8; ++i) {
      const float* pr = &p1t[e0 + 4 * i][hb * 16];
#pragma unroll
      for (int jb = 0; jb < 4; ++jb) {
        float4 pv = *(const float4*)(pr + jb * 4);
        acc[i] += xv[jb * 4 + 0] * pv.x + xv[jb * 4 + 1] * pv.y +
                  xv[jb * 4 + 2] * pv.z + xv[jb * 4 + 3] * pv.w;
      }
    }
  }
  unsigned short* op = t1b + (size_t)nc * 2048;
#pragma unroll
  for (int i = 0; i < 8; ++i) op[(e0 + 4 * i) * 64 + w] = to_bf16(acc[i]);
}

// ---------------------------------------------------------------------------
// k_t3: 9x9 depthwise conv on each (32,64) t1 plane, pad 4. One block per
// (n,c). t1 plane staged zero-padded f32 in LDS; branch-free register window.
// Output plane is [36][64] with 2 zero rows top/bottom (t4 halo, branch-free).
// ---------------------------------------------------------------------------
__global__ __launch_bounds__(256) void k_t3(const unsigned short* __restrict__ t1b,
                                            const float* __restrict__ p3,
                                            unsigned short* __restrict__ t3g) {
  const int nc = blockIdx.x;
  const int c = nc & 255;
  const int tid = threadIdx.x;
  __shared__ __align__(16) float t1s[40][76];  // 12160 B, zero borders
  for (int i = tid; i < 40 * 76; i += 256) (&t1s[0][0])[i] = 0.f;
  __syncthreads();
  {
    uint4 v = *(const uint4*)(t1b + (size_t)nc * 2048 + tid * 8);
    const unsigned short* vs = (const unsigned short*)&v;
    const int e = tid >> 3, w0 = (tid & 7) * 8;
    float f0[4], f1[4];
#pragma unroll
    for (int k = 0; k < 4; ++k) { f0[k] = from_bf16(vs[k]); f1[k] = from_bf16(vs[4 + k]); }
    *(float4*)&t1s[4 + e][4 + w0] = *(const float4*)f0;
    *(float4*)&t1s[4 + e][8 + w0] = *(const float4*)f1;
  }
  __syncthreads();
  unsigned short* plane = t3g + (size_t)nc * 2304;  // 36*64
  // zero halo rows 0,1,34,35
  if (tid < 32) {
    static const int zr[4] = {0, 1, 34, 35};
    int row = zr[tid >> 3], col = (tid & 7) * 8;
    uint4 z = make_uint4(0, 0, 0, 0);
    *(uint4*)(plane + row * 64 + col) = z;
  }
  const int e = tid >> 3, w0 = (tid & 7) * 8;
  const float* w3 = p3 + c * 81;
  float o[8];
#pragma unroll
  for (int k = 0; k < 8; ++k) o[k] = 0.f;
#pragma unroll
  for (int i = 0; i < 9; ++i) {
    float win[16];
    const float* r = &t1s[e + i][w0];
    *(float4*)&win[0]  = *(const float4*)(r);
    *(float4*)&win[4]  = *(const float4*)(r + 4);
    *(float4*)&win[8]  = *(const float4*)(r + 8);
    *(float4*)&win[12] = *(const float4*)(r + 12);
#pragma unroll
    for (int j = 0; j < 9; ++j) {
      float wt = w3[i * 9 + j];
#pragma unroll
      for (int k = 0; k < 8; ++k) o[k] += win[j + k] * wt;
    }
  }
  unsigned short ob[8];
#pragma unroll
  for (int k = 0; k < 8; ++k) ob[k] = to_bf16(o[k]);
  *(uint4*)(plane + (2 + e) * 64 + w0) = *(const uint4*)ob;
}

// ---------------------------------------------------------------------------
// k_t4k: (5,1) grouped conv (groups of 4 channels) over zero-padded t3 planes.
// One block per (n,c); pure global/L1 reads, no LDS, branch-free.
// ---------------------------------------------------------------------------
__global__ __launch_bounds__(256) void k_t4k(const unsigned short* __restrict__ t3g,
                                             const float* __restrict__ p4,
                                             unsigned short* __restrict__ t4b) {
  const int nc = blockIdx.x;
  const int c = nc & 255;
  const int tid = threadIdx.x;
  const int e = tid >> 3, w0 = (tid & 7) * 8;
  const float* w4 = p4 + c * 20;
  float acc[8];
#pragma unroll
  for (int k = 0; k < 8; ++k) acc[k] = 0.f;
#pragma unroll
  for (int ci = 0; ci < 4; ++ci) {
    const unsigned short* plane = t3g + (size_t)((nc & ~3) + ci) * 2304;
#pragma unroll
    for (int u = 0; u < 5; ++u) {
      uint4 v = *(const uint4*)(plane + (e + u) * 64 + w0);
      const unsigned short* vs = (const unsigned short*)&v;
      float wv = w4[ci * 5 + u];
#pragma unroll
      for (int k = 0; k < 8; ++k) acc[k] += from_bf16(vs[k]) * wv;
    }
  }
  unsigned short ob[8];
#pragma unroll
  for (int k = 0; k < 8; ++k) ob[k] = to_bf16(acc[k]);
  *(uint4*)(t4b + (size_t)nc * 2048 + e * 64 + w0) = *(const uint4*)ob;
}

// ---------------------------------------------------------------------------
// p5 [2048][768] f32 -> p5t [768][2048] bf16 (transpose + convert)
// ---------------------------------------------------------------------------
__global__ __launch_bounds__(256) void k_p5t(const float* __restrict__ p5,
                                             unsigned short* __restrict__ p5t) {
  const int f0 = blockIdx.x * 64;
  const int k0 = blockIdx.y * 64;
  const int tid = threadIdx.x;
  __shared__ __align__(16) unsigned short ls[64][264];
  int fl = tid & 63, k4 = tid >> 6;
  for (int i = 0; i < 16; ++i) {
    int kl = k4 * 16 + i;
    ls[fl][kl] = to_bf16(p5[(size_t)(k0 + kl) * F + f0 + fl]);
  }
  __syncthreads();
#pragma unroll
  for (int j = 0; j < 2; ++j) {
    int chunk = tid + 256 * j;
    int row = chunk >> 3, slot = chunk & 7;
    *(uint4*)(p5t + (size_t)(f0 + row) * K5 + k0 + slot * 8) = *(const uint4*)&ls[row][slot * 8];
  }
}

// ---------------------------------------------------------------------------
// x [n][c][h][w] f32 -> xt [n][64 + h*64+w + 64][c] bf16, zero pads
// ---------------------------------------------------------------------------
__global__ __launch_bounds__(256) void k_xt(const float* __restrict__ x,
                                            unsigned short* __restrict__ xt) {
  const int hi = blockIdx.x;   // 0..65
  const int n = blockIdx.y;
  const int tid = threadIdx.x;
  unsigned short* dst = xt + ((size_t)n * XROWS + hi * 64) * C;
  if (hi == 0 || hi == 65) {
    uint4 z = make_uint4(0, 0, 0, 0);
    uint4* d4 = (uint4*)dst;
#pragma unroll
    for (int i = 0; i < 8; ++i) d4[tid + 256 * i] = z;
    return;
  }
  const int h = hi - 1;
  __shared__ __align__(16) unsigned short ls[64][264];
  const float* xp = x + ((size_t)n * C) * HW + h * 64;
  int w = tid & 63, c4 = tid >> 6;
  for (int i = 0; i < 64; ++i) {
    int c = c4 * 64 + i;
    ls[w][c] = to_bf16(xp[(size_t)c * HW + w]);
  }
  __syncthreads();
#pragma unroll
  for (int j = 0; j < 8; ++j) {
    int chunk = tid + 256 * j;          // 2048 chunks of 16B
    int row = chunk >> 5, slot = chunk & 31;
    *(uint4*)(dst + row * C + slot * 8) = *(const uint4*)&ls[row][slot * 8];
  }
}

// ---------------------------------------------------------------------------
// k_t5m: t5[4096][768] f32 = t4b[4096][2048]bf16 x p5t^T.  64x64 tile ->
// 768 blocks (3/CU) for TLP; 4 waves as 2x2, wave-tile 32x32.
// ---------------------------------------------------------------------------
__global__ __launch_bounds__(256) void k_t5m(const unsigned short* __restrict__ A,
                                             const unsigned short* __restrict__ Bt,
                                             float* __restrict__ Cout) {
  const int n0 = blockIdx.x * 64;   // 12
  const int m0 = blockIdx.y * 64;   // 64
  const int tid = threadIdx.x;
  const int lane = tid & 63;
  const int wave = tid >> 6;
  const int wm = wave >> 1, wn = wave & 1;
  __shared__ __align__(16) short As[4096];
  __shared__ __align__(16) short Bs[4096];
  f32x4 acc[2][2] = {};
  const int lr = lane >> 3;
  const int ls = lane & 7;

  for (int k0 = 0; k0 < K5; k0 += 64) {
#pragma unroll
    for (int i = 0; i < 2; ++i) {
      int inst = wave * 2 + i;       // 0..7
      int r = inst * 8 + lr;         // 0..63
      int sw = ls ^ (r & 7);
      gload16((const char*)(A + (size_t)(m0 + r) * K5 + k0) + sw * 16,
              (char*)As + inst * 1024);
      gload16((const char*)(Bt + (size_t)(n0 + r) * K5 + k0) + sw * 16,
              (char*)Bs + inst * 1024);
    }
    __syncthreads();
#pragma unroll
    for (int kh = 0; kh < 2; ++kh) {
      s16x8 af[2], bf[2];
#pragma unroll
      for (int mi = 0; mi < 2; ++mi) {
        int row = wm * 32 + mi * 16 + (lane & 15);
        int byte = (row * 128 + kh * 64 + (lane >> 4) * 16) ^ ((row & 7) << 4);
        af[mi] = *(const s16x8*)((const char*)As + byte);
      }
#pragma unroll
      for (int ni = 0; ni < 2; ++ni) {
        int row = wn * 32 + ni * 16 + (lane & 15);
        int byte = (row * 128 + kh * 64 + (lane >> 4) * 16) ^ ((row & 7) << 4);
        bf[ni] = *(const s16x8*)((const char*)Bs + byte);
      }
#pragma unroll
      for (int mi = 0; mi < 2; ++mi)
#pragma unroll
        for (int ni = 0; ni < 2; ++ni)
          acc[mi][ni] = __builtin_amdgcn_mfma_f32_16x16x32_bf16(af[mi], bf[ni], acc[mi][ni], 0, 0, 0);
    }
    __syncthreads();
  }
#pragma unroll
  for (int mi = 0; mi < 2; ++mi) {
    int rbase = m0 + wm * 32 + mi * 16 + (lane >> 4) * 4;
#pragma unroll
    for (int ni = 0; ni < 2; ++ni) {
      int col = n0 + wn * 32 + ni * 16 + (lane & 15);
#pragma unroll
      for (int q = 0; q < 4; ++q)
        Cout[(size_t)(rbase + q) * F + col] = acc[mi][ni][q];
    }
  }
}

// ---------------------------------------------------------------------------
// k_t6: t5 f32 -> 3-tap dw conv (original f order) -> scale -> bf16 in f' order
// f' = kk*256 + c2  (f = 3*c2 + kk)
// ---------------------------------------------------------------------------
__global__ __launch_bounds__(256) void k_t6(const float* __restrict__ t5,
                                            const float* __restrict__ p6,
                                            unsigned short* __restrict__ t6b) {
  int idx = blockIdx.x * 256 + threadIdx.x;
  if (idx >= NB * C * F) return;
  int fp = idx % F;
  int nc = idx / F;
  int c = nc & 255;
  int c2 = fp & 255;
  int kk = fp >> 8;
  int f = 3 * c2 + kk;
  const float* row = t5 + (size_t)nc * F;
  const float* wt = p6 + c * 3;
  float acc = row[f] * wt[1];
  if (f > 0) acc += row[f - 1] * wt[0];
  if (f < F - 1) acc += row[f + 1] * wt[2];
  t6b[idx] = to_bf16(acc * 0.03608439182435161f);
}

// ---------------------------------------------------------------------------
// k_outm: out[n][256][4096] f32 = t6b[n][256][768] x B' (from xt, shifted rows)
// ---------------------------------------------------------------------------
__global__ __launch_bounds__(256) void k_outm(const unsigned short* __restrict__ t6b,
                                              const unsigned short* __restrict__ xt,
                                              float* __restrict__ outp) {
  const int p0 = blockIdx.x * 128;   // 32
  const int m0 = blockIdx.y * 128;   // 2
  const int n  = blockIdx.z;         // 16
  const int tid = threadIdx.x;
  const int lane = tid & 63;
  const int wave = tid >> 6;
  const int wm = wave >> 1, wn = wave & 1;
  __shared__ __align__(16) short As[8192];
  __shared__ __align__(16) short Bs[8192];
  f32x4 acc[4][4] = {};
  const int lr = lane >> 3;
  const int ls = lane & 7;
  const unsigned short* Abase = t6b + (size_t)(n * C) * F;
  const unsigned short* Xbase = xt + (size_t)n * XROWS * C;

  for (int kt = 0; kt < 12; ++kt) {
    int k0 = kt * 64;
    int kk = k0 >> 8;
    int c20 = k0 & 255;
#pragma unroll
    for (int i = 0; i < 4; ++i) {
      int inst = wave * 4 + i;
      int r = inst * 8 + lr;
      int sw = ls ^ (r & 7);
      gload16((const char*)(Abase + (size_t)(m0 + r) * F + k0) + sw * 16,
              (char*)As + inst * 1024);
      gload16((const char*)(Xbase + (size_t)(p0 + r + (kk << 6)) * C + c20) + sw * 16,
              (char*)Bs + inst * 1024);
    }
    __syncthreads();
#pragma unroll
    for (int kh = 0; kh < 2; ++kh) {
      s16x8 af[4], bf[4];
#pragma unroll
      for (int mi = 0; mi < 4; ++mi) {
        int row = wm * 64 + mi * 16 + (lane & 15);
        int byte = (row * 128 + kh * 64 + (lane >> 4) * 16) ^ ((row & 7) << 4);
        af[mi] = *(const s16x8*)((const char*)As + byte);
      }
#pragma unroll
      for (int ni = 0; ni < 4; ++ni) {
        int row = wn * 64 + ni * 16 + (lane & 15);
        int byte = (row * 128 + kh * 64 + (lane >> 4) * 16) ^ ((row & 7) << 4);
        bf[ni] = *(const s16x8*)((const char*)Bs + byte);
      }
#pragma unroll
      for (int mi = 0; mi < 4; ++mi)
#pragma unroll
        for (int ni = 0; ni < 4; ++ni)
          acc[mi][ni] = __builtin_amdgcn_mfma_f32_16x16x32_bf16(af[mi], bf[ni], acc[mi][ni], 0, 0, 0);
    }
    __syncthreads();
  }
  float* obase = outp + (size_t)(n * C) * HW;
#pragma unroll
  for (int mi = 0; mi < 4; ++mi) {
    int rbase = m0 + wm * 64 + mi * 16 + (lane >> 4) * 4;
#pragma unroll
    for (int ni = 0; ni < 4; ++ni) {
      int col = p0 + wn * 64 + ni * 16 + (lane & 15);
#pragma unroll
      for (int q = 0; q < 4; ++q)
        obase[(size_t)(rbase + q) * HW + col] = acc[mi][ni][q];
    }
  }
}

extern "C" void kernel_launch(void* const* d_in, const int* in_sizes, int n_in,
                              void* d_out, int out_size, void* d_ws, size_t ws_size,
                              hipStream_t stream) {
  (void)in_sizes; (void)n_in; (void)out_size; (void)ws_size;
  const float* x  = (const float*)d_in[0];
  const float* p1 = (const float*)d_in[1];
  const float* p3 = (const float*)d_in[2];
  const float* p4 = (const float*)d_in[3];
  const float* p5 = (const float*)d_in[4];
  const float* p6 = (const float*)d_in[5];
  float* out = (float*)d_out;

  char* ws = (char*)d_ws;
  // Lifetime-overlaid workspace (peak 51.4 MB):
  //  [0      , 18.87M): t3g  (k_t3 -> k_t4k); then t6b at [0, 6.29M) (k_t6 ->)
  //                      and xt at [6.29M, 40.89M) (k_xt -> k_outm)
  //  [18.87M , 35.65M): t1b  (k_t1 -> k_t3); then t4b (k_t4k -> k_t5m)
  //  [35.65M , 38.80M): p5t  (k_p5t -> k_t5m)
  //  [38.80M , 51.38M): t5   (k_t5m -> k_t6)
  unsigned short* t3g = (unsigned short*)ws;
  unsigned short* t1b = (unsigned short*)(ws + 18874368);
  unsigned short* t4b = (unsigned short*)(ws + 18874368);
  unsigned short* p5t = (unsigned short*)(ws + 35651584);
  float*          t5  = (float*)(ws + 38797312);
  unsigned short* t6b = (unsigned short*)ws;
  unsigned short* xt  = (unsigned short*)(ws + 6291456);

  k_t1 <<<dim3(NB * C), 256, 0, stream>>>(x, p1, t1b);
  k_t3 <<<dim3(NB * C), 256, 0, stream>>>(t1b, p3, t3g);
  k_t4k<<<dim3(NB * C), 256, 0, stream>>>(t3g, p4, t4b);
  k_p5t<<<dim3(12, 32), 256, 0, stream>>>(p5, p5t);
  k_t5m<<<dim3(12, 64), 256, 0, stream>>>(t4b, p5t, t5);
  k_t6 <<<dim3((NB * C * F + 255) / 256), 256, 0, stream>>>(t5, p6, t6b);
  k_xt <<<dim3(66, NB), 256, 0, stream>>>(x, xt);
  k_outm<<<dim3(32, 2, NB), 256, 0, stream>>>(t6b, xt, out);
}

// Round 8
// 167.071 us; speedup vs baseline: 1.3021x; 1.0055x over previous
//
#include <hip/hip_runtime.h>

#define NB 16
#define C  256
#define H  64
#define W  64
#define E  32
#define F  768
#define HW 4096
#define K5 2048
#define XROWS 4224   // 64 pad + 4096 + 64 pad

typedef __attribute__((ext_vector_type(4))) float f32x4;
typedef __attribute__((ext_vector_type(8))) short s16x8;

__device__ inline unsigned short to_bf16(float f) {
  union { float f; unsigned u; } v; v.f = f;
  unsigned u = v.u;
  u += 0x7fff + ((u >> 16) & 1);
  return (unsigned short)(u >> 16);
}

__device__ inline float from_bf16(unsigned short s) {
  union { unsigned u; float f; } v; v.u = ((unsigned)s) << 16;
  return v.f;
}

__device__ inline void gload16(const void* g, void* l) {
  __builtin_amdgcn_global_load_lds((const __attribute__((address_space(1))) unsigned int*)g,
                                   (__attribute__((address_space(3))) unsigned int*)l, 16, 0, 0);
}

// ---------------------------------------------------------------------------
// k_t1: t1b[nc][e*64+w] bf16 = sum_h x[nc][h][w] * p1[h][e].
// ---------------------------------------------------------------------------
__global__ __launch_bounds__(256) void k_t1(const float* __restrict__ x,
                                            const float* __restrict__ p1,
                                            unsigned short* __restrict__ t1b) {
  const int nc = blockIdx.x;
  const int tid = threadIdx.x;
  const int w = tid & 63;
  const int e0 = tid >> 6;  // 0..3
  __shared__ __align__(16) float p1t[32][68];  // 8.5 KB, p1t[e][h], +4 pad
  for (int i = tid; i < 2048; i += 256) {
    int h = i >> 5, e = i & 31;      // coalesced global read
    p1t[e][h] = p1[i];
  }
  __syncthreads();
  const float* xp = x + (size_t)nc * HW;
  float acc[8] = {0.f, 0.f, 0.f, 0.f, 0.f, 0.f, 0.f, 0.f};
#pragma unroll
  for (int hb = 0; hb < 4; ++hb) {
    float xv[16];
#pragma unroll
    for (int j = 0; j < 16; ++j) xv[j] = xp[(hb * 16 + j) * 64 + w];
#pragma unroll
    for (int i = 0; i < 8; ++i) {
      const float* pr = &p1t[e0 + 4 * i][hb * 16];
#pragma unroll
      for (int jb = 0; jb < 4; ++jb) {
        float4 pv = *(const float4*)(pr + jb * 4);
        acc[i] += xv[jb * 4 + 0] * pv.x + xv[jb * 4 + 1] * pv.y +
                  xv[jb * 4 + 2] * pv.z + xv[jb * 4 + 3] * pv.w;
      }
    }
  }
  unsigned short* op = t1b + (size_t)nc * 2048;
#pragma unroll
  for (int i = 0; i < 8; ++i) op[(e0 + 4 * i) * 64 + w] = to_bf16(acc[i]);
}

// ---------------------------------------------------------------------------
// k_t3: 9x9 depthwise conv on each (32,64) t1 plane, pad 4.
// ---------------------------------------------------------------------------
__global__ __launch_bounds__(256) void k_t3(const unsigned short* __restrict__ t1b,
                                            const float* __restrict__ p3,
                                            unsigned short* __restrict__ t3g) {
  const int nc = blockIdx.x;
  const int c = nc & 255;
  const int tid = threadIdx.x;
  __shared__ __align__(16) float t1s[40][76];  // 12160 B, zero borders
  for (int i = tid; i < 40 * 76; i += 256) (&t1s[0][0])[i] = 0.f;
  __syncthreads();
  {
    uint4 v = *(const uint4*)(t1b + (size_t)nc * 2048 + tid * 8);
    const unsigned short* vs = (const unsigned short*)&v;
    const int e = tid >> 3, w0 = (tid & 7) * 8;
    float f0[4], f1[4];
#pragma unroll
    for (int k = 0; k < 4; ++k) { f0[k] = from_bf16(vs[k]); f1[k] = from_bf16(vs[4 + k]); }
    *(float4*)&t1s[4 + e][4 + w0] = *(const float4*)f0;
    *(float4*)&t1s[4 + e][8 + w0] = *(const float4*)f1;
  }
  __syncthreads();
  unsigned short* plane = t3g + (size_t)nc * 2304;  // 36*64
  // zero halo rows 0,1,34,35
  if (tid < 32) {
    static const int zr[4] = {0, 1, 34, 35};
    int row = zr[tid >> 3], col = (tid & 7) * 8;
    uint4 z = make_uint4(0, 0, 0, 0);
    *(uint4*)(plane + row * 64 + col) = z;
  }
  const int e = tid >> 3, w0 = (tid & 7) * 8;
  const float* w3 = p3 + c * 81;
  float o[8];
#pragma unroll
  for (int k = 0; k < 8; ++k) o[k] = 0.f;
#pragma unroll
  for (int i = 0; i < 9; ++i) {
    float win[16];
    const float* r = &t1s[e + i][w0];
    *(float4*)&win[0]  = *(const float4*)(r);
    *(float4*)&win[4]  = *(const float4*)(r + 4);
    *(float4*)&win[8]  = *(const float4*)(r + 8);
    *(float4*)&win[12] = *(const float4*)(r + 12);
#pragma unroll
    for (int j = 0; j < 9; ++j) {
      float wt = w3[i * 9 + j];
#pragma unroll
      for (int k = 0; k < 8; ++k) o[k] += win[j + k] * wt;
    }
  }
  unsigned short ob[8];
#pragma unroll
  for (int k = 0; k < 8; ++k) ob[k] = to_bf16(o[k]);
  *(uint4*)(plane + (2 + e) * 64 + w0) = *(const uint4*)ob;
}

// ---------------------------------------------------------------------------
// k_t4k: (5,1) grouped conv (groups of 4 channels) over zero-padded t3 planes.
// ---------------------------------------------------------------------------
__global__ __launch_bounds__(256) void k_t4k(const unsigned short* __restrict__ t3g,
                                             const float* __restrict__ p4,
                                             unsigned short* __restrict__ t4b) {
  const int nc = blockIdx.x;
  const int c = nc & 255;
  const int tid = threadIdx.x;
  const int e = tid >> 3, w0 = (tid & 7) * 8;
  const float* w4 = p4 + c * 20;
  float acc[8];
#pragma unroll
  for (int k = 0; k < 8; ++k) acc[k] = 0.f;
#pragma unroll
  for (int ci = 0; ci < 4; ++ci) {
    const unsigned short* plane = t3g + (size_t)((nc & ~3) + ci) * 2304;
#pragma unroll
    for (int u = 0; u < 5; ++u) {
      uint4 v = *(const uint4*)(plane + (e + u) * 64 + w0);
      const unsigned short* vs = (const unsigned short*)&v;
      float wv = w4[ci * 5 + u];
#pragma unroll
      for (int k = 0; k < 8; ++k) acc[k] += from_bf16(vs[k]) * wv;
    }
  }
  unsigned short ob[8];
#pragma unroll
  for (int k = 0; k < 8; ++k) ob[k] = to_bf16(acc[k]);
  *(uint4*)(t4b + (size_t)nc * 2048 + e * 64 + w0) = *(const uint4*)ob;
}

// ---------------------------------------------------------------------------
// p5 [2048][768] f32 -> p5t [768][2048] bf16 (transpose + convert)
// ---------------------------------------------------------------------------
__global__ __launch_bounds__(256) void k_p5t(const float* __restrict__ p5,
                                             unsigned short* __restrict__ p5t) {
  const int f0 = blockIdx.x * 64;
  const int k0 = blockIdx.y * 64;
  const int tid = threadIdx.x;
  __shared__ __align__(16) unsigned short ls[64][264];
  int fl = tid & 63, k4 = tid >> 6;
  for (int i = 0; i < 16; ++i) {
    int kl = k4 * 16 + i;
    ls[fl][kl] = to_bf16(p5[(size_t)(k0 + kl) * F + f0 + fl]);
  }
  __syncthreads();
#pragma unroll
  for (int j = 0; j < 2; ++j) {
    int chunk = tid + 256 * j;
    int row = chunk >> 3, slot = chunk & 7;
    *(uint4*)(p5t + (size_t)(f0 + row) * K5 + k0 + slot * 8) = *(const uint4*)&ls[row][slot * 8];
  }
}

// ---------------------------------------------------------------------------
// x [n][c][h][w] f32 -> xt [n][64 + h*64+w + 64][c] bf16, zero pads
// ---------------------------------------------------------------------------
__global__ __launch_bounds__(256) void k_xt(const float* __restrict__ x,
                                            unsigned short* __restrict__ xt) {
  const int hi = blockIdx.x;   // 0..65
  const int n = blockIdx.y;
  const int tid = threadIdx.x;
  unsigned short* dst = xt + ((size_t)n * XROWS + hi * 64) * C;
  if (hi == 0 || hi == 65) {
    uint4 z = make_uint4(0, 0, 0, 0);
    uint4* d4 = (uint4*)dst;
#pragma unroll
    for (int i = 0; i < 8; ++i) d4[tid + 256 * i] = z;
    return;
  }
  const int h = hi - 1;
  __shared__ __align__(16) unsigned short ls[64][264];
  const float* xp = x + ((size_t)n * C) * HW + h * 64;
  int w = tid & 63, c4 = tid >> 6;
  for (int i = 0; i < 64; ++i) {
    int c = c4 * 64 + i;
    ls[w][c] = to_bf16(xp[(size_t)c * HW + w]);
  }
  __syncthreads();
#pragma unroll
  for (int j = 0; j < 8; ++j) {
    int chunk = tid + 256 * j;          // 2048 chunks of 16B
    int row = chunk >> 5, slot = chunk & 31;
    *(uint4*)(dst + row * C + slot * 8) = *(const uint4*)&ls[row][slot * 8];
  }
}

// ---------------------------------------------------------------------------
// k_t5m: t5[4096][768] f32 = t4b[4096][2048]bf16 x p5t^T.  64x64 tile,
// 2-phase double-buffered staging (T3 minimum recipe): issue next-tile
// global_load_lds BEFORE current tile's ds_read+MFMA; one barrier per tile.
// LDS 32 KB.
// ---------------------------------------------------------------------------
__global__ __launch_bounds__(256) void k_t5m(const unsigned short* __restrict__ A,
                                             const unsigned short* __restrict__ Bt,
                                             float* __restrict__ Cout) {
  const int n0 = blockIdx.x * 64;   // 12
  const int m0 = blockIdx.y * 64;   // 64
  const int tid = threadIdx.x;
  const int lane = tid & 63;
  const int wave = tid >> 6;
  const int wm = wave >> 1, wn = wave & 1;
  __shared__ __align__(16) short As[2][4096];
  __shared__ __align__(16) short Bs[2][4096];
  f32x4 acc[2][2] = {};
  const int lr = lane >> 3;
  const int ls = lane & 7;

  auto stage = [&](int b, int k0) {
#pragma unroll
    for (int i = 0; i < 2; ++i) {
      int inst = wave * 2 + i;       // 0..7
      int r = inst * 8 + lr;         // 0..63
      int sw = ls ^ (r & 7);
      gload16((const char*)(A + (size_t)(m0 + r) * K5 + k0) + sw * 16,
              (char*)As[b] + inst * 1024);
      gload16((const char*)(Bt + (size_t)(n0 + r) * K5 + k0) + sw * 16,
              (char*)Bs[b] + inst * 1024);
    }
  };

  stage(0, 0);
  __syncthreads();
  int buf = 0;
  for (int kt = 0; kt < 32; ++kt) {
    if (kt < 31) stage(buf ^ 1, (kt + 1) * 64);
#pragma unroll
    for (int kh = 0; kh < 2; ++kh) {
      s16x8 af[2], bf[2];
#pragma unroll
      for (int mi = 0; mi < 2; ++mi) {
        int row = wm * 32 + mi * 16 + (lane & 15);
        int byte = (row * 128 + kh * 64 + (lane >> 4) * 16) ^ ((row & 7) << 4);
        af[mi] = *(const s16x8*)((const char*)As[buf] + byte);
      }
#pragma unroll
      for (int ni = 0; ni < 2; ++ni) {
        int row = wn * 32 + ni * 16 + (lane & 15);
        int byte = (row * 128 + kh * 64 + (lane >> 4) * 16) ^ ((row & 7) << 4);
        bf[ni] = *(const s16x8*)((const char*)Bs[buf] + byte);
      }
#pragma unroll
      for (int mi = 0; mi < 2; ++mi)
#pragma unroll
        for (int ni = 0; ni < 2; ++ni)
          acc[mi][ni] = __builtin_amdgcn_mfma_f32_16x16x32_bf16(af[mi], bf[ni], acc[mi][ni], 0, 0, 0);
    }
    __syncthreads();
    buf ^= 1;
  }
#pragma unroll
  for (int mi = 0; mi < 2; ++mi) {
    int rbase = m0 + wm * 32 + mi * 16 + (lane >> 4) * 4;
#pragma unroll
    for (int ni = 0; ni < 2; ++ni) {
      int col = n0 + wn * 32 + ni * 16 + (lane & 15);
#pragma unroll
      for (int q = 0; q < 4; ++q)
        Cout[(size_t)(rbase + q) * F + col] = acc[mi][ni][q];
    }
  }
}

// ---------------------------------------------------------------------------
// k_t6: t5 f32 -> 3-tap dw conv (original f order) -> scale -> bf16 in f' order
// f' = kk*256 + c2  (f = 3*c2 + kk)
// ---------------------------------------------------------------------------
__global__ __launch_bounds__(256) void k_t6(const float* __restrict__ t5,
                                            const float* __restrict__ p6,
                                            unsigned short* __restrict__ t6b) {
  int idx = blockIdx.x * 256 + threadIdx.x;
  if (idx >= NB * C * F) return;
  int fp = idx % F;
  int nc = idx / F;
  int c = nc & 255;
  int c2 = fp & 255;
  int kk = fp >> 8;
  int f = 3 * c2 + kk;
  const float* row = t5 + (size_t)nc * F;
  const float* wt = p6 + c * 3;
  float acc = row[f] * wt[1];
  if (f > 0) acc += row[f - 1] * wt[0];
  if (f < F - 1) acc += row[f + 1] * wt[2];
  t6b[idx] = to_bf16(acc * 0.03608439182435161f);
}

// ---------------------------------------------------------------------------
// k_outm: out[n][256][4096] f32 = t6b[n][256][768] x B' (from xt, shifted
// rows). 128x128 tile, 2-phase double-buffered staging, one barrier per
// k-tile. LDS 64 KB.
// ---------------------------------------------------------------------------
__global__ __launch_bounds__(256) void k_outm(const unsigned short* __restrict__ t6b,
                                              const unsigned short* __restrict__ xt,
                                              float* __restrict__ outp) {
  const int p0 = blockIdx.x * 128;   // 32
  const int m0 = blockIdx.y * 128;   // 2
  const int n  = blockIdx.z;         // 16
  const int tid = threadIdx.x;
  const int lane = tid & 63;
  const int wave = tid >> 6;
  const int wm = wave >> 1, wn = wave & 1;
  __shared__ __align__(16) short As[2][8192];
  __shared__ __align__(16) short Bs[2][8192];
  f32x4 acc[4][4] = {};
  const int lr = lane >> 3;
  const int ls = lane & 7;
  const unsigned short* Abase = t6b + (size_t)(n * C) * F;
  const unsigned short* Xbase = xt + (size_t)n * XROWS * C;

  auto stage = [&](int b, int kt) {
    int k0 = kt * 64;
    int kk = k0 >> 8;
    int c20 = k0 & 255;
#pragma unroll
    for (int i = 0; i < 4; ++i) {
      int inst = wave * 4 + i;
      int r = inst * 8 + lr;
      int sw = ls ^ (r & 7);
      gload16((const char*)(Abase + (size_t)(m0 + r) * F + k0) + sw * 16,
              (char*)As[b] + inst * 1024);
      gload16((const char*)(Xbase + (size_t)(p0 + r + (kk << 6)) * C + c20) + sw * 16,
              (char*)Bs[b] + inst * 1024);
    }
  };

  stage(0, 0);
  __syncthreads();
  int buf = 0;
  for (int kt = 0; kt < 12; ++kt) {
    if (kt < 11) stage(buf ^ 1, kt + 1);
#pragma unroll
    for (int kh = 0; kh < 2; ++kh) {
      s16x8 af[4], bf[4];
#pragma unroll
      for (int mi = 0; mi < 4; ++mi) {
        int row = wm * 64 + mi * 16 + (lane & 15);
        int byte = (row * 128 + kh * 64 + (lane >> 4) * 16) ^ ((row & 7) << 4);
        af[mi] = *(const s16x8*)((const char*)As[buf] + byte);
      }
#pragma unroll
      for (int ni = 0; ni < 4; ++ni) {
        int row = wn * 64 + ni * 16 + (lane & 15);
        int byte = (row * 128 + kh * 64 + (lane >> 4) * 16) ^ ((row & 7) << 4);
        bf[ni] = *(const s16x8*)((const char*)Bs[buf] + byte);
      }
#pragma unroll
      for (int mi = 0; mi < 4; ++mi)
#pragma unroll
        for (int ni = 0; ni < 4; ++ni)
          acc[mi][ni] = __builtin_amdgcn_mfma_f32_16x16x32_bf16(af[mi], bf[ni], acc[mi][ni], 0, 0, 0);
    }
    __syncthreads();
    buf ^= 1;
  }
  float* obase = outp + (size_t)(n * C) * HW;
#pragma unroll
  for (int mi = 0; mi < 4; ++mi) {
    int rbase = m0 + wm * 64 + mi * 16 + (lane >> 4) * 4;
#pragma unroll
    for (int ni = 0; ni < 4; ++ni) {
      int col = p0 + wn * 64 + ni * 16 + (lane & 15);
#pragma unroll
      for (int q = 0; q < 4; ++q)
        obase[(size_t)(rbase + q) * HW + col] = acc[mi][ni][q];
    }
  }
}

extern "C" void kernel_launch(void* const* d_in, const int* in_sizes, int n_in,
                              void* d_out, int out_size, void* d_ws, size_t ws_size,
                              hipStream_t stream) {
  (void)in_sizes; (void)n_in; (void)out_size; (void)ws_size;
  const float* x  = (const float*)d_in[0];
  const float* p1 = (const float*)d_in[1];
  const float* p3 = (const float*)d_in[2];
  const float* p4 = (const float*)d_in[3];
  const float* p5 = (const float*)d_in[4];
  const float* p6 = (const float*)d_in[5];
  float* out = (float*)d_out;

  char* ws = (char*)d_ws;
  // Lifetime-overlaid workspace (peak 51.4 MB):
  //  [0      , 18.87M): t3g  (k_t3 -> k_t4k); then t6b at [0, 6.29M) (k_t6 ->)
  //                      and xt at [6.29M, 40.89M) (k_xt -> k_outm)
  //  [18.87M , 35.65M): t1b  (k_t1 -> k_t3); then t4b (k_t4k -> k_t5m)
  //  [35.65M , 38.80M): p5t  (k_p5t -> k_t5m)
  //  [38.80M , 51.38M): t5   (k_t5m -> k_t6)
  unsigned short* t3g = (unsigned short*)ws;
  unsigned short* t1b = (unsigned short*)(ws + 18874368);
  unsigned short* t4b = (unsigned short*)(ws + 18874368);
  unsigned short* p5t = (unsigned short*)(ws + 35651584);
  float*          t5  = (float*)(ws + 38797312);
  unsigned short* t6b = (unsigned short*)ws;
  unsigned short* xt  = (unsigned short*)(ws + 6291456);

  k_t1 <<<dim3(NB * C), 256, 0, stream>>>(x, p1, t1b);
  k_t3 <<<dim3(NB * C), 256, 0, stream>>>(t1b, p3, t3g);
  k_t4k<<<dim3(NB * C), 256, 0, stream>>>(t3g, p4, t4b);
  k_p5t<<<dim3(12, 32), 256, 0, stream>>>(p5, p5t);
  k_t5m<<<dim3(12, 64), 256, 0, stream>>>(t4b, p5t, t5);
  k_t6 <<<dim3((NB * C * F + 255) / 256), 256, 0, stream>>>(t5, p6, t6b);
  k_xt <<<dim3(66, NB), 256, 0, stream>>>(x, xt);
  k_outm<<<dim3(32, 2, NB), 256, 0, stream>>>(t6b, xt, out);
}